// Round 1
// baseline (934.396 us; speedup 1.0000x reference)
//
#include <hip/hip_runtime.h>

#define BB 64
#define PP 10000
#define EE 128
#define CC 100

// scatter decomposition
#define ESL 4                 // E-slices per row
#define SLICE 32              // elements per slice (= lanes per node group)
#define NP 8                  // P-chunks per batch
#define CHUNK (PP / NP)       // 1250 nodes per chunk
#define PSUM_STRIDE (CC * SLICE)                 // 3200 floats per (np,b,es) partial
#define PSUM_NPSTRIDE (BB * ESL * PSUM_STRIDE)   // 819200 floats per np

// ---------------------------------------------------------------------------
// Kernel 1: per-(batch, E-slice, P-chunk) segment-sum into a small (12.8 KB)
// LDS accumulator. Scalar 4B loads put every ds_add on bank==lane
// (conflict-free); merge is plain coalesced stores of partials (no global
// atomics). Partials live in the g_node output region (overwritten later by
// gather, after project has consumed them).
// ---------------------------------------------------------------------------
__global__ __launch_bounds__(256) void scatter_kernel(
    const float* __restrict__ nodes, const int* __restrict__ ids,
    float* __restrict__ psums, float* __restrict__ pcnts)
{
    __shared__ float s_acc[CC * SLICE];   // 12800 B, bank = (c*32+lane)%32 = lane
    __shared__ float s_cnt[CC];
    __shared__ int   s_ids[CHUNK];        // 5000 B

    const int tid = threadIdx.x;
    const int es  = blockIdx.x;           // 0..3
    const int b   = blockIdx.y;           // 0..63
    const int np  = blockIdx.z;           // 0..7

    for (int i = tid; i < CC * SLICE; i += 256) s_acc[i] = 0.f;
    if (tid < CC) s_cnt[tid] = 0.f;

    const int p0 = np * CHUNK;
    const int* idb = ids + b * PP + p0;
    for (int i = tid; i < CHUNK; i += 256) s_ids[i] = idb[i];
    __syncthreads();

    const int lane = tid & 31;            // element within slice
    const int sub  = tid >> 5;            // 8 node rows in flight
    const float* src = nodes + (size_t)b * PP * EE + (size_t)p0 * EE
                             + es * SLICE + lane;

    if (es == 0) {
#pragma unroll 4
        for (int p = sub; p < CHUNK; p += 8) {
            int c = s_ids[p];
            float v = src[(size_t)p * EE];
            if ((unsigned)c < CC) {
                atomicAdd(&s_acc[c * SLICE + lane], v);
                if (lane == 0) atomicAdd(&s_cnt[c], 1.0f);
            }
        }
    } else {
#pragma unroll 4
        for (int p = sub; p < CHUNK; p += 8) {
            int c = s_ids[p];
            float v = src[(size_t)p * EE];
            if ((unsigned)c < CC) atomicAdd(&s_acc[c * SLICE + lane], v);
        }
    }
    __syncthreads();

    float* out = psums + (size_t)((np * BB + b) * ESL + es) * PSUM_STRIDE;
    for (int i = tid; i < CC * SLICE; i += 256) out[i] = s_acc[i];
    if (es == 0) {
        float* oc = pcnts + (np * BB + b) * CC;
        for (int i = tid; i < CC; i += 256) oc[i] = s_cnt[i];
    }
}

// ---------------------------------------------------------------------------
// Kernel 2: reduce NP partials -> mean -> Linear(E,E).
// out[row][e] = bias[e] + (1/max(cnt,1)) * sum_k sums[row][k] * W[e][k]
// W^T staged in LDS stride-129 (conflict-free); row sums staged transposed
// [k][8] so a wave-uniform float4 broadcast serves 4 rows at once.
// ---------------------------------------------------------------------------
__global__ __launch_bounds__(256) void project_kernel(
    float* __restrict__ ce,              // [6400][128] out: projected embs
    const float* __restrict__ psums,     // [NP][64][4][100*32]
    const float* __restrict__ pcnts,     // [NP][64*100]
    const float* __restrict__ W,         // [128][128] row-major W[e][k]
    const float* __restrict__ bias)      // [128]
{
    __shared__ float s_wt[EE * 129];     // s_wt[k*129 + e] = W[e][k]
    __shared__ float s_mt[EE * 8];       // s_mt[k*8 + rr] = sums[row rr][k]
    __shared__ float s_inv[8];

    const int tid = threadIdx.x;
    for (int i = tid; i < EE * EE; i += 256) {
        int e = i >> 7, k = i & 127;
        s_wt[k * 129 + e] = W[i];
    }

    const int e   = tid & 127;
    const int sub = tid >> 7;            // 0..1, wave-uniform
    const float be = bias[e];
    const int row0 = blockIdx.x * 16;

    for (int j = 0; j < 2; ++j) {
        __syncthreads();  // s_wt ready (j=0) / previous compute done (j=1)
        if (tid < 8) {
            int row = row0 + j * 8 + tid;
            float s = 0.f;
#pragma unroll
            for (int np = 0; np < NP; ++np) s += pcnts[np * (BB * CC) + row];
            s_inv[tid] = 1.0f / fmaxf(s, 1.0f);
        }
        // stage 8 rows of raw sums (reducing the NP partials), transposed
        for (int i = tid; i < 8 * EE; i += 256) {
            int ee = i & 127, rr = i >> 7;
            int row = row0 + j * 8 + rr;
            int bb = row / CC, c = row % CC;
            const float* pp = psums + (size_t)(bb * ESL + (ee >> 5)) * PSUM_STRIDE
                                    + c * SLICE + (ee & 31);
            float s = 0.f;
#pragma unroll
            for (int np = 0; np < NP; ++np) s += pp[(size_t)np * PSUM_NPSTRIDE];
            s_mt[ee * 8 + rr] = s;
        }
        __syncthreads();

        float acc0 = 0.f, acc1 = 0.f, acc2 = 0.f, acc3 = 0.f;
        const float* wp = &s_wt[e];
        const float4* mp = (const float4*)s_mt;  // mp[k*2 + sub] = sums[4sub..4sub+3][k]
#pragma unroll 8
        for (int k = 0; k < 128; ++k) {
            float  w = wp[k * 129];
            float4 m = mp[k * 2 + sub];
            acc0 = fmaf(w, m.x, acc0);
            acc1 = fmaf(w, m.y, acc1);
            acc2 = fmaf(w, m.z, acc2);
            acc3 = fmaf(w, m.w, acc3);
        }
        const int rbase = row0 + j * 8 + sub * 4;
        ce[(size_t)(rbase + 0) * EE + e] = be + acc0 * s_inv[sub * 4 + 0];
        ce[(size_t)(rbase + 1) * EE + e] = be + acc1 * s_inv[sub * 4 + 1];
        ce[(size_t)(rbase + 2) * EE + e] = be + acc2 * s_inv[sub * 4 + 2];
        ce[(size_t)(rbase + 3) * EE + e] = be + acc3 * s_inv[sub * 4 + 3];
    }
}

// ---------------------------------------------------------------------------
// Kernel 3: gather projected cluster embeddings back per node.
// ce is 3.3 MB (L2-resident) -> read it directly, no LDS, no barrier.
// 32-lane group per node, float4 per lane; grid-stride over P.
// ---------------------------------------------------------------------------
__global__ __launch_bounds__(256) void gather_kernel(
    const int* __restrict__ ids, const float* __restrict__ ce,
    float* __restrict__ gn)
{
    const int tid  = threadIdx.x;
    const int lane = tid & 31;
    const int sub  = tid >> 5;
    const int b    = blockIdx.y;

    const int* idb = ids + b * PP;
    const float4* ceb = (const float4*)(ce + (size_t)b * CC * EE);
    float4* dst = (float4*)(gn + (size_t)b * PP * EE);

    for (int p = blockIdx.x * 8 + sub; p < PP; p += 32 * 8) {
        int c = idb[p];
        if ((unsigned)c >= CC) c = 0;   // safety (never taken)
        float4 v = ceb[(size_t)c * 32 + lane];
        dst[(size_t)p * 32 + lane] = v;
    }
}

extern "C" void kernel_launch(void* const* d_in, const int* in_sizes, int n_in,
                              void* d_out, int out_size, void* d_ws, size_t ws_size,
                              hipStream_t stream)
{
    const float* nodes = (const float*)d_in[0];
    const int*   ids   = (const int*)d_in[1];
    // d_in[2] = num_clusters (scalar, fixed at 100 — compile-time here)
    const float* W     = (const float*)d_in[3];
    const float* bias  = (const float*)d_in[4];

    float* out = (float*)d_out;
    float* ce  = out;                               // [64][100][128]
    float* gn  = out + (size_t)BB * CC * EE;        // [64][10000][128]

    // Scratch for scatter partials lives at the head of the gn region:
    // 26.2 MB of psums + 0.2 MB of pcnts << 327 MB; consumed by project,
    // then fully overwritten by gather. No memsets needed anywhere.
    float* psums = gn;
    float* pcnts = gn + (size_t)NP * PSUM_NPSTRIDE;

    hipLaunchKernelGGL(scatter_kernel, dim3(ESL, BB, NP), dim3(256), 0, stream,
                       nodes, ids, psums, pcnts);
    hipLaunchKernelGGL(project_kernel, dim3(BB * CC / 16), dim3(256), 0, stream,
                       ce, psums, pcnts, W, bias);
    hipLaunchKernelGGL(gather_kernel, dim3(32, BB), dim3(256), 0, stream,
                       ids, ce, gn);
}

// Round 3
// 886.655 us; speedup vs baseline: 1.0538x; 1.0538x over previous
//
#include <hip/hip_runtime.h>

#define BB 64
#define PP 10000
#define EE 128
#define CC 100
#define NP 16                  // P-chunks per batch
#define CHUNK (PP / NP)        // 625 nodes per chunk
#define ROWS (CC * EE)         // 12800 floats per partial
#define PLANE (CC * 32)        // 3200 floats per component-plane

typedef float v4f __attribute__((ext_vector_type(4)));

// ---------------------------------------------------------------------------
// Kernel 1: per-(batch, P-chunk) segment-sum of FULL 128-float rows.
// - v4f loads: 1 KB per wave-op (max MLP per instruction).
// - LDS accumulator in PLANAR layout: element e of cluster c lives at
//   s_acc[(e&3)*PLANE + c*32 + (e>>2)]  ->  ds bank == lane for every atomic
//   (2 lanes/bank per wave64 = free), zero conflicts by construction.
// - native-path f32 atomics via __hip_atomic_fetch_add (relaxed, workgroup)
//   instead of atomicAdd (which may lower to a CAS loop for IEEE floats).
// - merge: plain nontemporal stores of partials (no global atomics, no L3
//   pollution; psums are one-shot producer->consumer).
// ---------------------------------------------------------------------------
__global__ __launch_bounds__(256) void scatter_kernel(
    const float* __restrict__ nodes, const int* __restrict__ ids,
    float* __restrict__ psums, float* __restrict__ pcnts)
{
    __shared__ float s_acc[ROWS];     // 51200 B, planar [4][CC][32]
    __shared__ float s_cnt[CC];
    __shared__ int   s_ids[CHUNK];    // 2500 B

    const int tid = threadIdx.x;
    const int b   = blockIdx.x;       // 0..63
    const int np  = blockIdx.y;       // 0..15

    for (int i = tid; i < ROWS; i += 256) s_acc[i] = 0.f;
    if (tid < CC) s_cnt[tid] = 0.f;

    const int p0 = np * CHUNK;
    const int* idb = ids + b * PP + p0;
    for (int i = tid; i < CHUNK; i += 256) s_ids[i] = idb[i];
    __syncthreads();

    const int lane = tid & 31;        // float4 slot within a row
    const int sub  = tid >> 5;        // 8 node rows in flight per block step
    const v4f* src = (const v4f*)(nodes + (size_t)b * PP * EE
                                        + (size_t)p0 * EE);

#pragma unroll 4
    for (int p = sub; p < CHUNK; p += 8) {
        int c = s_ids[p];
        v4f v = src[(size_t)p * 32 + lane];   // 512 B contiguous per group
        if ((unsigned)c < CC) {
            // element e = 4*lane + j  ->  addr (j*PLANE + c*32 + lane)
            float* a = &s_acc[c * 32 + lane];
            __hip_atomic_fetch_add(a + 0 * PLANE, v.x, __ATOMIC_RELAXED, __HIP_MEMORY_SCOPE_WORKGROUP);
            __hip_atomic_fetch_add(a + 1 * PLANE, v.y, __ATOMIC_RELAXED, __HIP_MEMORY_SCOPE_WORKGROUP);
            __hip_atomic_fetch_add(a + 2 * PLANE, v.z, __ATOMIC_RELAXED, __HIP_MEMORY_SCOPE_WORKGROUP);
            __hip_atomic_fetch_add(a + 3 * PLANE, v.w, __ATOMIC_RELAXED, __HIP_MEMORY_SCOPE_WORKGROUP);
            if (lane == 0)
                __hip_atomic_fetch_add(&s_cnt[c], 1.0f, __ATOMIC_RELAXED, __HIP_MEMORY_SCOPE_WORKGROUP);
        }
    }
    __syncthreads();

    // coalesced wide nontemporal merge (psums keeps the planar layout)
    v4f* outp = (v4f*)(psums + (size_t)(np * BB + b) * ROWS);
    const v4f* accp = (const v4f*)s_acc;
    for (int i = tid; i < ROWS / 4; i += 256)
        __builtin_nontemporal_store(accp[i], &outp[i]);
    float* oc = pcnts + (np * BB + b) * CC;
    if (tid < CC) __builtin_nontemporal_store(s_cnt[tid], &oc[tid]);
}

// ---------------------------------------------------------------------------
// Kernel 2: reduce NP planar partials -> mean -> Linear(E,E).
// out[row][e] = bias[e] + (1/max(cnt,1)) * sum_k sums[row][k] * W[e][k]
// W^T staged in LDS stride-129 (conflict-free); row sums staged transposed
// [k][8] so a wave-uniform float4 broadcast serves 4 rows at once.
// ---------------------------------------------------------------------------
__global__ __launch_bounds__(256) void project_kernel(
    float* __restrict__ ce,              // [6400][128] out: projected embs
    const float* __restrict__ psums,     // [NP][64][4][CC][32] planar
    const float* __restrict__ pcnts,     // [NP][64*100]
    const float* __restrict__ W,         // [128][128] row-major W[e][k]
    const float* __restrict__ bias)      // [128]
{
    __shared__ float s_wt[EE * 129];     // s_wt[k*129 + e] = W[e][k]
    __shared__ float s_mt[EE * 8];       // s_mt[k*8 + rr] = sums[row rr][k]
    __shared__ float s_inv[8];

    const int tid = threadIdx.x;
    for (int i = tid; i < EE * EE; i += 256) {
        int e = i >> 7, k = i & 127;
        s_wt[k * 129 + e] = W[i];
    }

    const int e   = tid & 127;
    const int sub = tid >> 7;            // 0..1, wave-uniform
    const float be = bias[e];
    const int row0 = blockIdx.x * 16;

    for (int j = 0; j < 2; ++j) {
        __syncthreads();  // s_wt ready (j=0) / previous compute done (j=1)
        if (tid < 8) {
            int row = row0 + j * 8 + tid;
            float s = 0.f;
#pragma unroll
            for (int np = 0; np < NP; ++np)
                s += pcnts[np * (BB * CC) + row];
            s_inv[tid] = 1.0f / fmaxf(s, 1.0f);
        }
        // stage 8 rows of raw sums (reducing NP planar partials), transposed
        for (int i = tid; i < 8 * EE; i += 256) {
            int rr = i >> 7, idx = i & 127;       // idx = (plane j, slot l)
            int row = row0 + j * 8 + rr;
            int bb = row / CC, c = row % CC;
            const float* pp = psums + (size_t)bb * ROWS
                                    + (idx >> 5) * PLANE + c * 32 + (idx & 31);
            float s = 0.f;
#pragma unroll
            for (int np = 0; np < NP; ++np)
                s += __builtin_nontemporal_load(pp + (size_t)np * BB * ROWS);
            int ee = ((idx & 31) << 2) | (idx >> 5);   // e = 4*l + j
            s_mt[ee * 8 + rr] = s;
        }
        __syncthreads();

        float acc0 = 0.f, acc1 = 0.f, acc2 = 0.f, acc3 = 0.f;
        const float* wp = &s_wt[e];
        const v4f* mp = (const v4f*)s_mt;  // mp[k*2+sub] = sums[4sub..4sub+3][k]
#pragma unroll 8
        for (int k = 0; k < 128; ++k) {
            float w = wp[k * 129];
            v4f   m = mp[k * 2 + sub];
            acc0 = fmaf(w, m.x, acc0);
            acc1 = fmaf(w, m.y, acc1);
            acc2 = fmaf(w, m.z, acc2);
            acc3 = fmaf(w, m.w, acc3);
        }
        const int rbase = row0 + j * 8 + sub * 4;
        ce[(size_t)(rbase + 0) * EE + e] = be + acc0 * s_inv[sub * 4 + 0];
        ce[(size_t)(rbase + 1) * EE + e] = be + acc1 * s_inv[sub * 4 + 1];
        ce[(size_t)(rbase + 2) * EE + e] = be + acc2 * s_inv[sub * 4 + 2];
        ce[(size_t)(rbase + 3) * EE + e] = be + acc3 * s_inv[sub * 4 + 3];
    }
}

// ---------------------------------------------------------------------------
// Kernel 3: gather projected cluster embeddings back per node.
// ce is 3.3 MB (L2-resident) -> read directly; write gn with NONTEMPORAL
// stores (one-shot output; keep it out of L2/L3 so nodes stays resident
// for the next iteration's scatter).
// ---------------------------------------------------------------------------
__global__ __launch_bounds__(256) void gather_kernel(
    const int* __restrict__ ids, const float* __restrict__ ce,
    float* __restrict__ gn)
{
    const int tid  = threadIdx.x;
    const int lane = tid & 31;
    const int sub  = tid >> 5;
    const int b    = blockIdx.y;

    const int* idb = ids + b * PP;
    const v4f* ceb = (const v4f*)(ce + (size_t)b * CC * EE);
    v4f* dst = (v4f*)(gn + (size_t)b * PP * EE);

#pragma unroll 2
    for (int p = blockIdx.x * 8 + sub; p < PP; p += 32 * 8) {
        int c = idb[p];
        if ((unsigned)c >= CC) c = 0;   // safety (never taken)
        v4f v = ceb[(size_t)c * 32 + lane];
        __builtin_nontemporal_store(v, &dst[(size_t)p * 32 + lane]);
    }
}

extern "C" void kernel_launch(void* const* d_in, const int* in_sizes, int n_in,
                              void* d_out, int out_size, void* d_ws, size_t ws_size,
                              hipStream_t stream)
{
    const float* nodes = (const float*)d_in[0];
    const int*   ids   = (const int*)d_in[1];
    // d_in[2] = num_clusters (scalar, fixed at 100 — compile-time here)
    const float* W     = (const float*)d_in[3];
    const float* bias  = (const float*)d_in[4];

    float* out = (float*)d_out;
    float* ce  = out;                               // [64][100][128]
    float* gn  = out + (size_t)BB * CC * EE;        // [64][10000][128]

    // Scratch partials live at the head of the gn region: 52.4 MB psums +
    // 0.4 MB pcnts << 327 MB; consumed by project, then fully overwritten
    // by gather. No memsets needed anywhere.
    float* psums = gn;
    float* pcnts = gn + (size_t)NP * BB * ROWS;

    hipLaunchKernelGGL(scatter_kernel, dim3(BB, NP), dim3(256), 0, stream,
                       nodes, ids, psums, pcnts);
    hipLaunchKernelGGL(project_kernel, dim3(BB * CC / 16), dim3(256), 0, stream,
                       ce, psums, pcnts, W, bias);
    hipLaunchKernelGGL(gather_kernel, dim3(32, BB), dim3(256), 0, stream,
                       ids, ce, gn);
}